// Round 6
// baseline (318.350 us; speedup 1.0000x reference)
//
#include <hip/hip_runtime.h>
#include <hip/hip_cooperative_groups.h>
#include <math.h>

#define H 4096
#define INP 512
#define OUTN 64
#define H4 (H / 4)            // 1024 fx4 per row
#define NB 256                // one block per CU (cooperative co-residency)
#define NT_ 1024              // threads per block
#define RPB (H / NB)          // 16 rows per block

// Native clang vector: accepted by __builtin_nontemporal_{load,store}.
typedef float fx4 __attribute__((ext_vector_type(4)));

namespace cg = cooperative_groups;

// ---------------------------------------------------------------------------
// Single cooperative kernel. Evidence (R0-R5): k_partial is pinned at ~50 us
// (~3.8 TB/s delivered blend) across 3 orthogonal shape/ILP variants, while
// >=90 us of the 246 us total lives BETWEEN kernels (top-5 bound: all other
// kernels <= 51 us; 52+51+51 << 246). So: one kernel, two grid.sync()s, no
// junction drains, partial shrunk 16 MB -> 4 MB, hebb re-read in phase 3 hits
// the same XCD's L2/L3 (same block that streamed it in phase 1).
//
// phase 1: partial[b][j] = sum_{i in rows(b)} hidden[i]*(w[i,j]+plas[i,j]*hebb[i,j])
// phase 2: x[j] = relu(sum_b partial[b][j] + W_i2h[j,:]@inp + b_i2h[j])
// phase 4: out[o] = tanh(x@W_h2o[o,:]+b)      (blocks 0..63, right after sync)
// phase 3: hebb_out rows(b) = (1-lr)*hebb + lr*hidden[i]*x
// ---------------------------------------------------------------------------
__global__ __launch_bounds__(NT_) void k_fused(
    const float* __restrict__ inp,
    const float* __restrict__ hidden,
    const float* __restrict__ hebb,
    const float* __restrict__ W_i2h,
    const float* __restrict__ b_i2h,
    const float* __restrict__ w,
    const float* __restrict__ plas,
    const float* __restrict__ learn,
    const float* __restrict__ W_h2o,
    const float* __restrict__ b_h2o,
    float* __restrict__ partial,
    float* __restrict__ x,
    float* __restrict__ hebb_out,
    float* __restrict__ out)
{
    cg::grid_group grid = cg::this_grid();
    const int t  = threadIdx.x;          // 0..1023: one fx4 column per thread
    const int b  = blockIdx.x;           // 0..255
    const int i0 = b * RPB;

    const fx4* __restrict__ w4 = (const fx4*)w;
    const fx4* __restrict__ p4 = (const fx4*)plas;
    const fx4* __restrict__ h4 = (const fx4*)hebb;

    // ---------------- phase 1: row-chunk matvec partial ----------------
    // Each block streams 16 full rows x 3 arrays = 768 KB sequentially.
    // w/plas single-use -> NT (protect L3 residency of hebb for phase 3).
    fx4 acc = (fx4)(0.f);
    {
        size_t idx = (size_t)i0 * H4 + t;
#pragma unroll 4
        for (int r = 0; r < RPB; ++r) {
            const float hv = hidden[i0 + r];               // wave-uniform
            const fx4 hb = h4[idx];
            const fx4 wv = __builtin_nontemporal_load(w4 + idx);
            const fx4 pv = __builtin_nontemporal_load(p4 + idx);
            acc += hv * (wv + pv * hb);
            idx += H4;
        }
    }
    ((fx4*)partial)[(size_t)b * H4 + t] = acc;

    grid.sync();

    // ---------------- phase 2: finish x for j in [b*16, b*16+16) ----------------
    // wave jj handles column j = b*16+jj; lane l sums s = l,l+64,l+128,l+192.
    // The block's partial tile is 256 s x 16 j = 16 KB -> L1-resident after
    // first touch (each 64B line covers exactly the block's 16 j's).
    {
        const int jj = t >> 6;
        const int l  = t & 63;
        const int j  = b * 16 + jj;
        float sum = 0.f;
#pragma unroll
        for (int k = 0; k < 4; ++k)
            sum += partial[(size_t)(l + 64 * k) * H + j];

        // i2h dot: lane l covers inp[l*8 .. l*8+8)
        const fx4* __restrict__ row4 = (const fx4*)(W_i2h + (size_t)j * INP);
        const fx4* __restrict__ in4  = (const fx4*)inp;
        const fx4 a0 = row4[l * 2],     a1 = row4[l * 2 + 1];
        const fx4 c0 = in4[l * 2],      c1 = in4[l * 2 + 1];
        sum += a0.x * c0.x + a0.y * c0.y + a0.z * c0.z + a0.w * c0.w
             + a1.x * c1.x + a1.y * c1.y + a1.z * c1.z + a1.w * c1.w;

#pragma unroll
        for (int off = 32; off > 0; off >>= 1)
            sum += __shfl_down(sum, off, 64);
        if (l == 0) {
            const float pre = sum + b_i2h[j];
            x[j] = pre > 0.f ? pre : 0.f;
        }
    }

    grid.sync();

    const fx4* __restrict__ x4 = (const fx4*)x;

    // ---------------- phase 4 (blocks 0..63): output gemv ----------------
    if (b < OUTN) {
        const fx4* __restrict__ row4 = (const fx4*)(W_h2o + (size_t)b * H);
        const fx4 aa = row4[t];
        const fx4 xx = x4[t];
        float s = aa.x * xx.x + aa.y * xx.y + aa.z * xx.z + aa.w * xx.w;
#pragma unroll
        for (int off = 32; off > 0; off >>= 1)
            s += __shfl_down(s, off, 64);
        __shared__ float red[NT_ / 64];
        if ((t & 63) == 0) red[t >> 6] = s;
        __syncthreads();
        if (t == 0) {
            float tot = 0.f;
#pragma unroll
            for (int u = 0; u < NT_ / 64; ++u) tot += red[u];
            out[b] = tanhf(tot + b_h2o[b]);
        }
    }

    // ---------------- phase 3: hebb update for rows(b) ----------------
    // Same block that streamed these hebb rows in phase 1 -> same XCD L2/L3.
    {
        const float lr   = learn[0];
        const float om   = 1.f - lr;
        const fx4 xt = x4[t];
        size_t idx = (size_t)i0 * H4 + t;
#pragma unroll 4
        for (int r = 0; r < RPB; ++r) {
            const float coef = lr * hidden[i0 + r];
            const fx4 hb = h4[idx];
            __builtin_nontemporal_store(om * hb + coef * xt, (fx4*)hebb_out + idx);
            idx += H4;
        }
    }
}

// ===========================================================================
// Fallback 3-kernel path (proven R5 code) in case cooperative launch fails.
// ===========================================================================
#define SPLITS 1024
#define RPS (H / SPLITS)

__global__ __launch_bounds__(256) void k_partial(
    const float* __restrict__ hidden,
    const float* __restrict__ w,
    const float* __restrict__ plas,
    const float* __restrict__ hebb,
    float* __restrict__ partial)
{
    const int t  = threadIdx.x;
    const int s  = blockIdx.x;
    const int i0 = s * RPS;
    const fx4* __restrict__ w4 = (const fx4*)w;
    const fx4* __restrict__ p4 = (const fx4*)plas;
    const fx4* __restrict__ h4 = (const fx4*)hebb;

    fx4 acc[4];
#pragma unroll
    for (int q = 0; q < 4; ++q) acc[q] = (fx4)(0.f);
    const size_t r0 = (size_t)i0 * H4 + t;
#pragma unroll
    for (int r = 0; r < RPS; ++r) {
        const float hv = hidden[i0 + r];
#pragma unroll
        for (int q = 0; q < 4; ++q) {
            const size_t idx = r0 + (size_t)r * H4 + q * 256;
            const fx4 hb = h4[idx];
            const fx4 wv = __builtin_nontemporal_load(w4 + idx);
            const fx4 pv = __builtin_nontemporal_load(p4 + idx);
            acc[q] += hv * (wv + pv * hb);
        }
    }
    fx4* __restrict__ o4 = (fx4*)partial + (size_t)s * H4 + t;
#pragma unroll
    for (int q = 0; q < 4; ++q) o4[q * 256] = acc[q];
}

__global__ __launch_bounds__(1024) void k_reduce_x(
    const float* __restrict__ partial,
    const float* __restrict__ inp,
    const float* __restrict__ W_i2h,
    const float* __restrict__ b_i2h,
    float* __restrict__ x_out)
{
    const int jl  = threadIdx.x & 31;
    const int grp = threadIdx.x >> 5;
    const int j   = blockIdx.x * 32 + jl;
    float sum = 0.f;
    const float* __restrict__ p = partial + (size_t)grp * (SPLITS / 32) * H + j;
#pragma unroll
    for (int s = 0; s < SPLITS / 32; ++s)
        sum += p[(size_t)s * H];
    const fx4* __restrict__ row4 = (const fx4*)(W_i2h + (size_t)j * INP);
    const fx4* __restrict__ in4  = (const fx4*)inp;
#pragma unroll
    for (int c = 0; c < 4; ++c) {
        const fx4 a = row4[grp * 4 + c];
        const fx4 b = in4[grp * 4 + c];
        sum += a.x * b.x + a.y * b.y + a.z * b.z + a.w * b.w;
    }
    __shared__ float red[32][33];
    red[grp][jl] = sum;
    __syncthreads();
    if (threadIdx.x < 32) {
        float tsum = 0.f;
#pragma unroll
        for (int g = 0; g < 32; ++g) tsum += red[g][jl];
        const float pre = tsum + b_i2h[j];
        x_out[j] = pre > 0.f ? pre : 0.f;
    }
}

__global__ __launch_bounds__(256) void k_tail(
    const float* __restrict__ hebb,
    const float* __restrict__ hidden,
    const float* __restrict__ x,
    const float* __restrict__ learn,
    const float* __restrict__ W_h2o,
    const float* __restrict__ b_h2o,
    float* __restrict__ hebb_out,
    float* __restrict__ out)
{
    if (blockIdx.x < H) {
        const int i = blockIdx.x;
        const float lr   = learn[0];
        const float om   = 1.f - lr;
        const float coef = lr * hidden[i];
        const fx4* __restrict__ hb4 = (const fx4*)hebb + (size_t)i * H4;
        const fx4* __restrict__ xx4 = (const fx4*)x;
        fx4* __restrict__ o4 = (fx4*)hebb_out + (size_t)i * H4;
        const int t = threadIdx.x;
#pragma unroll
        for (int q = 0; q < 4; ++q)
            __builtin_nontemporal_store(om * hb4[t + q * 256] + coef * xx4[t + q * 256],
                                        o4 + t + q * 256);
    } else {
        const int o = blockIdx.x - H;
        const fx4* __restrict__ row4 = (const fx4*)(W_h2o + (size_t)o * H);
        const fx4* __restrict__ x4   = (const fx4*)x;
        float sum = 0.f;
#pragma unroll
        for (int c = threadIdx.x; c < H4; c += 256) {
            const fx4 a = row4[c];
            const fx4 b = x4[c];
            sum += a.x * b.x + a.y * b.y + a.z * b.z + a.w * b.w;
        }
#pragma unroll
        for (int off = 32; off > 0; off >>= 1)
            sum += __shfl_down(sum, off, 64);
        __shared__ float red[4];
        const int lane = threadIdx.x & 63;
        const int wave = threadIdx.x >> 6;
        if (lane == 0) red[wave] = sum;
        __syncthreads();
        if (threadIdx.x == 0) {
            const float ssum = red[0] + red[1] + red[2] + red[3];
            out[o] = tanhf(ssum + b_h2o[o]);
        }
    }
}

extern "C" void kernel_launch(void* const* d_in, const int* in_sizes, int n_in,
                              void* d_out, int out_size, void* d_ws, size_t ws_size,
                              hipStream_t stream)
{
    const float* inp    = (const float*)d_in[0];
    const float* hidden = (const float*)d_in[1];
    const float* hebb   = (const float*)d_in[2];
    const float* W_i2h  = (const float*)d_in[3];
    const float* b_i2h  = (const float*)d_in[4];
    const float* w      = (const float*)d_in[5];
    const float* plas   = (const float*)d_in[6];
    const float* learn  = (const float*)d_in[7];
    const float* W_h2o  = (const float*)d_in[8];
    const float* b_h2o  = (const float*)d_in[9];

    float* out      = (float*)d_out;        // [64]
    float* x        = out + OUTN;           // [4096]
    float* hebb_out = x + H;                // [4096*4096]

    // Fused path needs 256*4096 floats = 4 MB of scratch.
    // Prefer d_ws; else borrow the first 4 MB of hebb_out (rows 0..255):
    // phase 2 reads partial before phase 3 writes those rows (grid.sync between).
    const size_t part_bytes_fused = (size_t)NB * H * sizeof(float);
    float* partial = (ws_size >= part_bytes_fused) ? (float*)d_ws : hebb_out;

    void* args[] = {
        (void*)&inp, (void*)&hidden, (void*)&hebb, (void*)&W_i2h, (void*)&b_i2h,
        (void*)&w, (void*)&plas, (void*)&learn, (void*)&W_h2o, (void*)&b_h2o,
        (void*)&partial, (void*)&x, (void*)&hebb_out, (void*)&out
    };
    hipError_t err = hipLaunchCooperativeKernel((const void*)k_fused,
                                                dim3(NB), dim3(NT_),
                                                args, 0, stream);
    if (err == hipSuccess) return;

    // ---- fallback: proven 3-kernel path (R5) ----
    const size_t part_bytes = (size_t)SPLITS * H * sizeof(float);
    float* partial2 = (ws_size >= part_bytes) ? (float*)d_ws : hebb_out;
    k_partial<<<SPLITS, 256, 0, stream>>>(hidden, w, plas, hebb, partial2);
    k_reduce_x<<<H / 32, 1024, 0, stream>>>(partial2, inp, W_i2h, b_i2h, x);
    k_tail<<<H + OUTN, 256, 0, stream>>>(hebb, hidden, x, learn, W_h2o, b_h2o, hebb_out, out);
}

// Round 7
// 254.807 us; speedup vs baseline: 1.2494x; 1.2494x over previous
//
#include <hip/hip_runtime.h>
#include <math.h>

#define H 4096
#define INP 512
#define OUTN 64
#define H4 (H / 4)                    // 1024 float4 per row
#define SPLITS 512
#define RPS (H / SPLITS)              // 8 rows per split

// Native clang vector: accepted by __builtin_nontemporal_{load,store}.
typedef float fx4 __attribute__((ext_vector_type(4)));

// ---------------------------------------------------------------------------
// K1: partial[s][j] = sum_{i in split s} hidden[i]*(w[i,j] + plas[i,j]*hebb[i,j])
// grid (4, 512) = 2048 blocks (R2 shape: best measured 49-51 us).
// R7 change: NO nontemporal loads. Inputs total 192 MB <= 256 MB L3 — with
// regular (allocating) loads the whole set becomes L3-resident across bench
// iterations. R2-R5's NT loads on w/plas forced a 98 MB HBM re-fetch every
// iteration at ~2 TB/s — the pacing component. NT is kept ONLY on the
// hebb_out store stream (write-only; must not evict the cached inputs).
// ---------------------------------------------------------------------------
__global__ __launch_bounds__(256) void k_partial(
    const float* __restrict__ hidden,
    const float* __restrict__ w,
    const float* __restrict__ plas,
    const float* __restrict__ hebb,
    float* __restrict__ partial)
{
    const int col4 = blockIdx.x * 256 + threadIdx.x;   // 0..1023
    const int i0   = blockIdx.y * RPS;
    const fx4* __restrict__ w4 = (const fx4*)w;
    const fx4* __restrict__ p4 = (const fx4*)plas;
    const fx4* __restrict__ h4 = (const fx4*)hebb;

    fx4 acc = (fx4)(0.f);
    size_t idx = (size_t)i0 * H4 + col4;
#pragma unroll
    for (int r = 0; r < RPS; r += 2) {
        const float hv0 = hidden[i0 + r];              // wave-uniform
        const float hv1 = hidden[i0 + r + 1];
        const fx4 wv0 = w4[idx];
        const fx4 pv0 = p4[idx];
        const fx4 hb0 = h4[idx];
        const fx4 wv1 = w4[idx + H4];
        const fx4 pv1 = p4[idx + H4];
        const fx4 hb1 = h4[idx + H4];
        acc += hv0 * (wv0 + pv0 * hb0) + hv1 * (wv1 + pv1 * hb1);
        idx += 2 * (size_t)H4;
    }
    ((fx4*)partial)[(size_t)blockIdx.y * H4 + col4] = acc;
}

// ---------------------------------------------------------------------------
// K2: x[j] = relu( sum_s partial[s][j] + W_i2h[j,:]@inp + b[j] )
// 1024-thread blocks: 32 s-groups x 32 j-columns; grid = H/32 = 128 blocks.
// partial (8 MB) was just written -> L2/L3 hot; reads along j are coalesced.
// ---------------------------------------------------------------------------
__global__ __launch_bounds__(1024) void k_reduce_x(
    const float* __restrict__ partial,
    const float* __restrict__ inp,
    const float* __restrict__ W_i2h,
    const float* __restrict__ b_i2h,
    float* __restrict__ x_out)
{
    const int jl  = threadIdx.x & 31;
    const int grp = threadIdx.x >> 5;          // 0..31
    const int j   = blockIdx.x * 32 + jl;

    // split-K reduction: group grp owns s in [grp*16, grp*16+16)
    float sum = 0.f;
    const float* __restrict__ p = partial + (size_t)grp * (SPLITS / 32) * H + j;
#pragma unroll
    for (int s = 0; s < SPLITS / 32; ++s)      // 16
        sum += p[(size_t)s * H];

    // i2h partial dot: group grp owns float4 k-range [grp*4, grp*4+4)
    const fx4* __restrict__ row4 = (const fx4*)(W_i2h + (size_t)j * INP);
    const fx4* __restrict__ in4  = (const fx4*)inp;
#pragma unroll
    for (int c = 0; c < 4; ++c) {
        const fx4 a = row4[grp * 4 + c];
        const fx4 b = in4[grp * 4 + c];
        sum += a.x * b.x + a.y * b.y + a.z * b.z + a.w * b.w;
    }

    __shared__ float red[32][33];              // +1 pad: conflict-free column read
    red[grp][jl] = sum;
    __syncthreads();
    if (threadIdx.x < 32) {
        float tsum = 0.f;
#pragma unroll
        for (int g = 0; g < 32; ++g) tsum += red[g][jl];
        const float pre = tsum + b_i2h[j];
        x_out[j] = pre > 0.f ? pre : 0.f;
    }
}

// ---------------------------------------------------------------------------
// K3 (fused tail): blocks [0,H) do the hebb row update; blocks [H, H+OUTN)
// compute out[o] = tanh(x @ W_h2o[o,:] + b).
// hebb loads regular (L3-resident from K1); hebb_out NT stores (write-only
// stream — bypass L3 so it cannot evict the cached inputs).
// ---------------------------------------------------------------------------
__global__ __launch_bounds__(256) void k_tail(
    const float* __restrict__ hebb,
    const float* __restrict__ hidden,
    const float* __restrict__ x,
    const float* __restrict__ learn,
    const float* __restrict__ W_h2o,
    const float* __restrict__ b_h2o,
    float* __restrict__ hebb_out,
    float* __restrict__ out)
{
    if (blockIdx.x < H) {
        const int i = blockIdx.x;
        const float lr   = learn[0];
        const float om   = 1.f - lr;
        const float coef = lr * hidden[i];
        const fx4* __restrict__ hb4 = (const fx4*)hebb + (size_t)i * H4;
        const fx4* __restrict__ xx4 = (const fx4*)x;
        fx4* __restrict__ o4 = (fx4*)hebb_out + (size_t)i * H4;
        const int t = threadIdx.x;
#pragma unroll
        for (int q = 0; q < 4; ++q)
            __builtin_nontemporal_store(om * hb4[t + q * 256] + coef * xx4[t + q * 256],
                                        o4 + t + q * 256);
    } else {
        const int o = blockIdx.x - H;          // 0..63
        const fx4* __restrict__ row4 = (const fx4*)(W_h2o + (size_t)o * H);
        const fx4* __restrict__ x4   = (const fx4*)x;
        float sum = 0.f;
#pragma unroll
        for (int c = threadIdx.x; c < H4; c += 256) {
            const fx4 a = row4[c];
            const fx4 b = x4[c];
            sum += a.x * b.x + a.y * b.y + a.z * b.z + a.w * b.w;
        }
#pragma unroll
        for (int off = 32; off > 0; off >>= 1)
            sum += __shfl_down(sum, off, 64);
        __shared__ float red[4];
        const int lane = threadIdx.x & 63;
        const int wave = threadIdx.x >> 6;
        if (lane == 0) red[wave] = sum;
        __syncthreads();
        if (threadIdx.x == 0) {
            const float ssum = red[0] + red[1] + red[2] + red[3];
            out[o] = tanhf(ssum + b_h2o[o]);
        }
    }
}

extern "C" void kernel_launch(void* const* d_in, const int* in_sizes, int n_in,
                              void* d_out, int out_size, void* d_ws, size_t ws_size,
                              hipStream_t stream)
{
    const float* inp    = (const float*)d_in[0];
    const float* hidden = (const float*)d_in[1];
    const float* hebb   = (const float*)d_in[2];
    const float* W_i2h  = (const float*)d_in[3];
    const float* b_i2h  = (const float*)d_in[4];
    const float* w      = (const float*)d_in[5];
    const float* plas   = (const float*)d_in[6];
    const float* learn  = (const float*)d_in[7];
    const float* W_h2o  = (const float*)d_in[8];
    const float* b_h2o  = (const float*)d_in[9];

    float* out      = (float*)d_out;        // [64]
    float* x        = out + OUTN;           // [4096]
    float* hebb_out = x + H;                // [4096*4096]

    // Scratch for split-K partials: 512*4096 floats = 8 MB.
    // Prefer d_ws; else borrow the (not-yet-written) hebb output region —
    // stream order guarantees k_reduce_x consumes it before k_tail overwrites.
    const size_t part_bytes = (size_t)SPLITS * H * sizeof(float);
    float* partial = (ws_size >= part_bytes) ? (float*)d_ws : hebb_out;

    k_partial<<<dim3(H4 / 256, SPLITS), 256, 0, stream>>>(hidden, w, plas, hebb, partial);
    k_reduce_x<<<H / 32, 1024, 0, stream>>>(partial, inp, W_i2h, b_i2h, x);
    k_tail<<<H + OUTN, 256, 0, stream>>>(hebb, hidden, x, learn, W_h2o, b_h2o, hebb_out, out);
}